// Round 18
// baseline (82.864 us; speedup 1.0000x reference)
//
#include <hip/hip_runtime.h>
#include <math.h>

// ---------------------------------------------------------------------------
// CAM module — R18: R17 + quad-buffered conv staging (depth-2 pipeline).
//   k_prep:        [Wq;Wk] -> tiled hi/lo bf16
//   k_conv_energy: 64-col tile, 4 waves. B staged into a RING OF 4 buffers
//                  2 steps ahead; barrier every 2 steps (8 total). Stage
//                  writes leave the consumer critical path (T3/T4-lite).
//   k_softmax_M:   reduce 64 partials, softmax, Mt bf16-tiled, ob.
//   k_out:         out = Mt @ X + ob (R17 — at HBM ceiling).
// Numerics: bf16-RTN q/k FAILS (R4) — hi/lo split required on q/k/energy.
// R15: 32x32 MFMA kills ILP. R12: throughput-bound. R13: native cvt.
// Race audit (every-2 barrier): interval {s,s+1} reads buf[s&3],[(s+1)&3],
// writes buf[(s+2)&3],[(s+3)&3] — disjoint under any wave skew.
// ---------------------------------------------------------------------------

typedef float f32x4 __attribute__((ext_vector_type(4)));
typedef short s16x8 __attribute__((ext_vector_type(8)));

__device__ __forceinline__ unsigned short f2bf(float f) {
  union { __bf16 b; unsigned short u; } v;
  v.b = (__bf16)f;            // HW RNE; pairs fuse to v_cvt_pk_bf16_f32
  return v.u;
}
__device__ __forceinline__ float bf2f(unsigned short h) {
  union { unsigned u; float f; } v; v.u = ((unsigned)h) << 16;
  return v.f;
}
__device__ __forceinline__ unsigned pack2(unsigned short a, unsigned short b) {
  return (unsigned)a | ((unsigned)b << 16);
}

// ---------------- Kernel 0: W -> tiled hi/lo bf16 --------------------------
__global__ __launch_bounds__(256) void k_prep(
    const float* __restrict__ Wq, const float* __restrict__ Wk,
    unsigned short* __restrict__ Wth, unsigned short* __restrict__ Wtl) {
  const int f = (blockIdx.x * 256 + threadIdx.x) * 4;
  const int row = f >> 9;
  const int k   = f & 511;
  const float* src = (row < 128) ? &Wq[row * 512 + k] : &Wk[(row - 128) * 512 + k];
  float4 v = *(const float4*)src;
  unsigned short h0 = f2bf(v.x), h1 = f2bf(v.y), h2 = f2bf(v.z), h3 = f2bf(v.w);
  unsigned short l0 = f2bf(v.x - bf2f(h0)), l1 = f2bf(v.y - bf2f(h1));
  unsigned short l2 = f2bf(v.z - bf2f(h2)), l3 = f2bf(v.w - bf2f(h3));
  const int di = (k >> 5) * 8192 + row * 32 + (k & 31);
  *(ushort4*)&Wth[di] = make_ushort4(h0, h1, h2, h3);
  *(ushort4*)&Wtl[di] = make_ushort4(l0, l1, l2, l3);
}

// ---------------- Kernel 1: fused conv + energy partial --------------------
// grid (64 nt, 8 b), 256 thr = 4 waves. Rows 0-255, cols nt*64..+63.
// K=512 in 16 unrolled steps; B ring-of-4 (buf c at c*5120 u16; hi,+2560 lo).
__global__ __launch_bounds__(256, 3) void k_conv_energy(
    const float* __restrict__ x,
    const unsigned short* __restrict__ Wth, const unsigned short* __restrict__ Wtl,
    const float* __restrict__ bq, const float* __restrict__ bk,
    float* __restrict__ epart) {
  __shared__ unsigned short LDS[20480];   // 40 KiB (conv ring) / 32 KiB (energy)
  unsigned short* Th = LDS;               // energy chunk hi (256*32 u16)
  unsigned short* Tl = LDS + 8192;        // energy chunk lo

  const int t = threadIdx.x;
  const int nt = blockIdx.x, b = blockIdx.y;
  const int w = t >> 6, lane = t & 63;
  const int lrow = lane & 15, lkb = lane >> 4;

  // B staging map: pp=(ci_l,kh); thread i16 stages output cols i16+16g.
  const int pp = t >> 4;
  const int ci_l = pp >> 1, kh = pp & 1;
  const int i16 = t & 15;
  const int klb = ci_l * 4 + kh * 2;
  const float* xb = x + ((size_t)b << 21);
  const float* xrow = xb + (size_t)ci_l * 16384 + (2 * nt + kh) * 128 + 2 * i16;

  f32x4 acc[4][4];
#pragma unroll
  for (int m = 0; m < 4; ++m)
#pragma unroll
    for (int n = 0; n < 4; ++n) acc[m][n] = (f32x4){0.f, 0.f, 0.f, 0.f};

  s16x8 pfh[4], pfl[4];         // A fragments for current step (depth-1)
  float2 pv[2][4];              // x ping-pong: at step s, pv[s&1] = x(s+2)
  const int aoff = (w * 64 + lrow) * 32 + lkb * 8;

  // -------- prologue: A(0); x(0)->buf0; x(1)->buf1; x(2)->pv[0] ------------
#pragma unroll
  for (int m = 0; m < 4; ++m) {
    pfh[m] = *(const s16x8*)&Wth[aoff + m * 512];
    pfl[m] = *(const s16x8*)&Wtl[aoff + m * 512];
  }
#pragma unroll
  for (int s0 = 0; s0 < 2; ++s0) {
    unsigned short* Nh = LDS + s0 * 5120;
    unsigned short* Nl = Nh + 2560;
    const float* xr = xrow + (size_t)s0 * 8 * 16384;
#pragma unroll
    for (int g = 0; g < 4; ++g) {
      float2 v = *(const float2*)&xr[32 * g];
      const int n = i16 + 16 * g;
      unsigned short hx = f2bf(v.x), hy = f2bf(v.y);
      *(unsigned*)&Nh[n * 40 + klb] = pack2(hx, hy);
      *(unsigned*)&Nl[n * 40 + klb] = pack2(f2bf(v.x - bf2f(hx)), f2bf(v.y - bf2f(hy)));
    }
  }
#pragma unroll
  for (int g = 0; g < 4; ++g)
    pv[0][g] = *(const float2*)&xrow[(size_t)2 * 8 * 16384 + 32 * g];
  __syncthreads();

  // -------- main loop: barrier every 2 steps, staging 2 ahead --------------
#pragma unroll
  for (int step = 0; step < 16; ++step) {
    // B fragments for THIS step from buf[step&3] (staged >=1 barrier ago)
    const unsigned short* Bh = LDS + (step & 3) * 5120;
    const unsigned short* Bl = Bh + 2560;
    s16x8 bfh[4], bfl[4];
#pragma unroll
    for (int nf = 0; nf < 4; ++nf) {
      const int bidx = (nf * 16 + lrow) * 40 + lkb * 8;
      bfh[nf] = *(const s16x8*)&Bh[bidx];
      bfl[nf] = *(const s16x8*)&Bl[bidx];
    }
    // MFMA on A(s) x B(s)
#pragma unroll
    for (int m = 0; m < 4; ++m)
#pragma unroll
      for (int n = 0; n < 4; ++n) {
        acc[m][n] = __builtin_amdgcn_mfma_f32_16x16x32_bf16(pfh[m], bfh[n], acc[m][n], 0, 0, 0);
        acc[m][n] = __builtin_amdgcn_mfma_f32_16x16x32_bf16(pfh[m], bfl[n], acc[m][n], 0, 0, 0);
        acc[m][n] = __builtin_amdgcn_mfma_f32_16x16x32_bf16(pfl[m], bfh[n], acc[m][n], 0, 0, 0);
      }
    // A(s+1)
    if (step < 15) {
      const unsigned short* Wh_n = Wth + (step + 1) * 8192;
      const unsigned short* Wl_n = Wtl + (step + 1) * 8192;
#pragma unroll
      for (int m = 0; m < 4; ++m) {
        pfh[m] = *(const s16x8*)&Wh_n[aoff + m * 512];
        pfl[m] = *(const s16x8*)&Wl_n[aoff + m * 512];
      }
    }
    // x(s+3) -> pv[(s+1)&1]
    if (step + 3 < 16) {
#pragma unroll
      for (int g = 0; g < 4; ++g)
        pv[(step + 1) & 1][g] =
            *(const float2*)&xrow[(size_t)(step + 3) * 8 * 16384 + 32 * g];
    }
    // stage x(s+2) = pv[s&1] -> buf[(s+2)&3]
    if (step + 2 < 16) {
      unsigned short* Nh = LDS + ((step + 2) & 3) * 5120;
      unsigned short* Nl = Nh + 2560;
#pragma unroll
      for (int g = 0; g < 4; ++g) {
        const int n = i16 + 16 * g;
        unsigned short hx = f2bf(pv[step & 1][g].x), hy = f2bf(pv[step & 1][g].y);
        *(unsigned*)&Nh[n * 40 + klb] = pack2(hx, hy);
        *(unsigned*)&Nl[n * 40 + klb] = pack2(f2bf(pv[step & 1][g].x - bf2f(hx)),
                                              f2bf(pv[step & 1][g].y - bf2f(hy)));
      }
    }
    // barrier every 2 steps (end of odd steps), none after the last
    if ((step & 1) == 1 && step < 15) {
      asm volatile("s_waitcnt lgkmcnt(0)" ::: "memory");
      __builtin_amdgcn_s_barrier();
    }
  }
  __syncthreads();   // full drain before LDS repurpose

  // ---- phase 2+3: energy in two 32-col K-chunks (32 KB tile) --------------
  const float* biasp = (w < 2) ? bq : bk;
  const int rb = (w & 1) * 64;
  float biasr[16];
#pragma unroll
  for (int m = 0; m < 4; ++m)
#pragma unroll
    for (int i = 0; i < 4; ++i)
      biasr[m * 4 + i] = biasp[rb + m * 16 + (lane >> 4) * 4 + i];

  f32x4 e[4][4];
#pragma unroll
  for (int m = 0; m < 4; ++m)
#pragma unroll
    for (int n = 0; n < 4; ++n) e[m][n] = (f32x4){0.f, 0.f, 0.f, 0.f};

  const int mrow0 = (w >> 1) * 64;
  const int nrow0 = 128 + (w & 1) * 64;

#pragma unroll
  for (int ks = 0; ks < 2; ++ks) {
#pragma unroll
    for (int m = 0; m < 4; ++m) {
      const int r0 = w * 64 + m * 16 + (lane >> 4) * 4;
#pragma unroll
      for (int nn = 0; nn < 2; ++nn) {
        const int n = 2 * ks + nn;
        const int cl = nn * 16 + lrow;
        const int cl8 = cl >> 3, c7 = cl & 7;
#pragma unroll
        for (int i = 0; i < 4; ++i) {
          const int r = r0 + i;
          const float vv = acc[m][n][i] + biasr[m * 4 + i];
          const unsigned short h = f2bf(vv);
          const unsigned short l = f2bf(vv - bf2f(h));
          const int ad = r * 32 + ((cl8 ^ (r & 3)) << 3) + c7;
          Th[ad] = h;
          Tl[ad] = l;
        }
      }
    }
    __syncthreads();
    {
      s16x8 qh[4], ql[4], kh8[4], kl8[4];
#pragma unroll
      for (int m = 0; m < 4; ++m) {
        const int r = mrow0 + m * 16 + lrow;
        const int ad = r * 32 + ((lkb ^ (r & 3)) << 3);
        qh[m] = *(const s16x8*)&Th[ad];
        ql[m] = *(const s16x8*)&Tl[ad];
      }
#pragma unroll
      for (int n = 0; n < 4; ++n) {
        const int r = nrow0 + n * 16 + lrow;
        const int ad = r * 32 + ((lkb ^ (r & 3)) << 3);
        kh8[n] = *(const s16x8*)&Th[ad];
        kl8[n] = *(const s16x8*)&Tl[ad];
      }
#pragma unroll
      for (int m = 0; m < 4; ++m)
#pragma unroll
        for (int n = 0; n < 4; ++n) {
          e[m][n] = __builtin_amdgcn_mfma_f32_16x16x32_bf16(qh[m], kh8[n], e[m][n], 0, 0, 0);
          e[m][n] = __builtin_amdgcn_mfma_f32_16x16x32_bf16(qh[m], kl8[n], e[m][n], 0, 0, 0);
          e[m][n] = __builtin_amdgcn_mfma_f32_16x16x32_bf16(ql[m], kh8[n], e[m][n], 0, 0, 0);
        }
    }
    if (ks == 0) __syncthreads();
  }

  float* ep = epart + ((size_t)b * 64 + nt) * 16384;
#pragma unroll
  for (int m = 0; m < 4; ++m) {
    const int qr = (w >> 1) * 64 + m * 16 + (lane >> 4) * 4;
#pragma unroll
    for (int n = 0; n < 4; ++n) {
      const int kr = (w & 1) * 64 + n * 16 + lrow;
#pragma unroll
      for (int i = 0; i < 4; ++i) ep[(size_t)(qr + i) * 128 + kr] = e[m][n][i];
    }
  }
}

// ---------------- Kernel 2: reduce + softmax + Mt(bf16 tiled) + ob ---------
__global__ __launch_bounds__(256) void k_softmax_M(
    const float* __restrict__ epart, const float* __restrict__ Wv,
    const float* __restrict__ bv, unsigned short* __restrict__ Mt,
    float* __restrict__ outbb) {
  __shared__ float As[4][128];
  const int t = threadIdx.x;
  const int wid = t >> 6, lane = t & 63;
  const int b = blockIdx.x >> 5;
  const int c = (blockIdx.x & 31) * 4 + wid;
  const int d0 = lane * 2;

  float2 s = make_float2(0.f, 0.f);
#pragma unroll 4
  for (int p = 0; p < 64; ++p) {
    float2 e = *(const float2*)&epart[((size_t)b * 64 + p) * 16384 + c * 128 + d0];
    s.x += e.x; s.y += e.y;
  }
  float mn = fminf(s.x, s.y);
#pragma unroll
  for (int off = 1; off < 64; off <<= 1) mn = fminf(mn, __shfl_xor(mn, off));
  const float p0 = expf(mn - s.x);
  const float p1 = expf(mn - s.y);
  float tot = p0 + p1;
#pragma unroll
  for (int off = 1; off < 64; off <<= 1) tot += __shfl_xor(tot, off);
  const float inv = 1.f / tot;
  const float a0 = p0 * inv, a1 = p1 * inv;

  const float2 bvv = *(const float2*)&bv[d0];
  float ob = a0 * bvv.x + a1 * bvv.y;
#pragma unroll
  for (int off = 1; off < 64; off <<= 1) ob += __shfl_xor(ob, off);
  if (lane == 0) outbb[b * 128 + c] = ob;

  As[wid][d0] = a0;
  As[wid][d0 + 1] = a1;   // wave-local write->read, lockstep-safe
  float m0 = 0.f, m1 = 0.f;
#pragma unroll 4
  for (int d = 0; d < 128; ++d) {
    const float a = As[wid][d];
    const float2 wv = *(const float2*)&Wv[d * 128 + d0];
    m0 = fmaf(a, wv.x, m0);
    m1 = fmaf(a, wv.y, m1);
  }
  const int sk = lane >> 4;
  const int ko = (lane * 2) & 31;
  *(unsigned*)&Mt[(size_t)b * 16384 + sk * 4096 + c * 32 + ko] =
      pack2(f2bf(m0), f2bf(m1));
}

// ---------------- Kernel 3: out = Mt @ X + ob (R17 verbatim) ---------------
__global__ __launch_bounds__(256) void k_out(
    const float* __restrict__ x, const unsigned short* __restrict__ Mt,
    const float* __restrict__ outbb, float* __restrict__ out) {
  __shared__ unsigned short Xs[10240];
  const int t = threadIdx.x;
  const int nt = blockIdx.x, b = blockIdx.y;
  const int wid = t >> 6, lane = t & 63;
  const int wr = wid >> 1, wc = wid & 1;
  const int lrow = lane & 15, lkb = lane >> 4;
  const int xkl = (t >> 5) * 4;
  const int xc0 = (t & 31) * 4;

  const float* xb = x + ((size_t)b << 21);
  const unsigned short* Mb = Mt + (size_t)b * 16384;
  float* ob = out + ((size_t)b << 21);

  f32x4 acc[4][4];
#pragma unroll
  for (int m = 0; m < 4; ++m)
#pragma unroll
    for (int n = 0; n < 4; ++n) acc[m][n] = (f32x4){0.f, 0.f, 0.f, 0.f};

  float4 pv[2][4];
#pragma unroll
  for (int q = 0; q < 4; ++q) {
    float4 v = *(const float4*)&xb[(size_t)(xkl + q) * 16384 + nt * 128 + xc0];
    Xs[(xc0 + 0) * 40 + xkl + q] = f2bf(v.x);
    Xs[(xc0 + 1) * 40 + xkl + q] = f2bf(v.y);
    Xs[(xc0 + 2) * 40 + xkl + q] = f2bf(v.z);
    Xs[(xc0 + 3) * 40 + xkl + q] = f2bf(v.w);
  }
#pragma unroll
  for (int q = 0; q < 4; ++q)
    pv[1][q] = *(const float4*)&xb[(size_t)(32 + xkl + q) * 16384 + nt * 128 + xc0];
  __syncthreads();

#pragma unroll
  for (int step = 0; step < 4; ++step) {
    const int cur = step & 1;
    const unsigned short* Bx = Xs + cur * 5120;
    s16x8 bf[4];
#pragma unroll
    for (int n = 0; n < 4; ++n)
      bf[n] = *(const s16x8*)&Bx[(wc * 64 + n * 16 + lrow) * 40 + lkb * 8];
    s16x8 af[4];
#pragma unroll
    for (int m = 0; m < 4; ++m)
      af[m] = *(const s16x8*)&Mb[step * 4096 + (wr * 64 + m * 16 + lrow) * 32 + lkb * 8];
    if (step < 2) {
#pragma unroll
      for (int q = 0; q < 4; ++q)
        pv[cur][q] = *(const float4*)&xb[(size_t)((step + 2) * 32 + xkl + q) * 16384 + nt * 128 + xc0];
    }
#pragma unroll
    for (int m = 0; m < 4; ++m)
#pragma unroll
      for (int n = 0; n < 4; ++n)
        acc[m][n] = __builtin_amdgcn_mfma_f32_16x16x32_bf16(af[m], bf[n], acc[m][n], 0, 0, 0);
    if (step < 3) {
      unsigned short* Nx = Xs + (cur ^ 1) * 5120;
#pragma unroll
      for (int q = 0; q < 4; ++q) {
        Nx[(xc0 + 0) * 40 + xkl + q] = f2bf(pv[cur ^ 1][q].x);
        Nx[(xc0 + 1) * 40 + xkl + q] = f2bf(pv[cur ^ 1][q].y);
        Nx[(xc0 + 2) * 40 + xkl + q] = f2bf(pv[cur ^ 1][q].z);
        Nx[(xc0 + 3) * 40 + xkl + q] = f2bf(pv[cur ^ 1][q].w);
      }
      asm volatile("s_waitcnt lgkmcnt(0)" ::: "memory");
      __builtin_amdgcn_s_barrier();
    }
  }
#pragma unroll
  for (int m = 0; m < 4; ++m) {
    const int r0 = wr * 64 + m * 16 + (lane >> 4) * 4;
#pragma unroll
    for (int n = 0; n < 4; ++n) {
      const int gc = nt * 128 + wc * 64 + n * 16 + (lane & 15);
#pragma unroll
      for (int i = 0; i < 4; ++i) {
        const int row = r0 + i;
        ob[(size_t)row * 16384 + gc] = acc[m][n][i] + outbb[b * 128 + row];
      }
    }
  }
}

// ---------------------------------------------------------------------------
extern "C" void kernel_launch(void* const* d_in, const int* in_sizes, int n_in,
                              void* d_out, int out_size, void* d_ws, size_t ws_size,
                              hipStream_t stream) {
  const float* x  = (const float*)d_in[0];
  const float* Wq = (const float*)d_in[1];
  const float* bq = (const float*)d_in[2];
  const float* Wk = (const float*)d_in[3];
  const float* bk = (const float*)d_in[4];
  const float* Wv = (const float*)d_in[5];
  const float* bv = (const float*)d_in[6];
  float* out = (float*)d_out;
  char* ws = (char*)d_ws;

  float* epart = (float*)ws;                               // 32 MiB
  unsigned short* Mt = (unsigned short*)(ws + 33554432);   // 256 KiB (bf16)
  float* outbb = (float*)(ws + 33816576);                  // 4 KiB
  unsigned short* Wth = (unsigned short*)(ws + 33820672);  // 256 KiB
  unsigned short* Wtl = (unsigned short*)(ws + 34082816);  // 256 KiB

  hipLaunchKernelGGL(k_prep, dim3(128), dim3(256), 0, stream, Wq, Wk, Wth, Wtl);
  hipLaunchKernelGGL(k_conv_energy, dim3(64, 8), dim3(256), 0, stream,
                     x, Wth, Wtl, bq, bk, epart);
  hipLaunchKernelGGL(k_softmax_M, dim3(256), dim3(256), 0, stream,
                     epart, Wv, bv, Mt, outbb);
  hipLaunchKernelGGL(k_out, dim3(128, 8), dim3(256), 0, stream,
                     x, Mt, outbb, out);
}

// Round 19
// 81.215 us; speedup vs baseline: 1.0203x; 1.0203x over previous
//
#include <hip/hip_runtime.h>
#include <math.h>

// ---------------------------------------------------------------------------
// CAM module — R19 = R17 verbatim (measured best: 81.0 us).
//   k_prep:        [Wq;Wk] -> tiled hi/lo bf16, fragment-coalesced layout
//   k_conv_energy: 64-col tile, 4 waves, 32KB LDS, 16x16 MFMA hi/lo split,
//                  B dbuf + lgkm-only raw barrier, chunked energy.
//   k_softmax_M:   reduce 64 partials, softmax(rowmin-e), Mt bf16-tiled, ob.
//   k_out:         out = Mt @ X + ob. A-frags global->VGPR (L2), X dbuf LDS.
// Numerics: bf16-RTN q/k FAILS (R4: 0.203) — hi/lo split required.
// Search closed: conv variants R8-R18 all 38.6-42us (multi-pipe sum bound:
// L2 7.8 + HBM 5.7 + LDS 5 + MFMA 3.5 + VALU 5 + energy tail 4 per CU).
// k_out at HBM ceiling (128MB -> ~20us). R15: 32x32 MFMA kills ILP.
// ---------------------------------------------------------------------------

typedef float f32x4 __attribute__((ext_vector_type(4)));
typedef short s16x8 __attribute__((ext_vector_type(8)));

__device__ __forceinline__ unsigned short f2bf(float f) {
  union { __bf16 b; unsigned short u; } v;
  v.b = (__bf16)f;            // HW RNE convert; pairs fuse to v_cvt_pk_bf16_f32
  return v.u;
}
__device__ __forceinline__ float bf2f(unsigned short h) {
  union { unsigned u; float f; } v; v.u = ((unsigned)h) << 16;
  return v.f;
}
__device__ __forceinline__ unsigned pack2(unsigned short a, unsigned short b) {
  return (unsigned)a | ((unsigned)b << 16);
}

// ---------------- Kernel 0: W -> tiled hi/lo bf16 --------------------------
__global__ __launch_bounds__(256) void k_prep(
    const float* __restrict__ Wq, const float* __restrict__ Wk,
    unsigned short* __restrict__ Wth, unsigned short* __restrict__ Wtl) {
  const int f = (blockIdx.x * 256 + threadIdx.x) * 4;
  const int row = f >> 9;
  const int k   = f & 511;
  const float* src = (row < 128) ? &Wq[row * 512 + k] : &Wk[(row - 128) * 512 + k];
  float4 v = *(const float4*)src;
  unsigned short h0 = f2bf(v.x), h1 = f2bf(v.y), h2 = f2bf(v.z), h3 = f2bf(v.w);
  unsigned short l0 = f2bf(v.x - bf2f(h0)), l1 = f2bf(v.y - bf2f(h1));
  unsigned short l2 = f2bf(v.z - bf2f(h2)), l3 = f2bf(v.w - bf2f(h3));
  const int di = (k >> 5) * 8192 + row * 32 + (k & 31);
  *(ushort4*)&Wth[di] = make_ushort4(h0, h1, h2, h3);
  *(ushort4*)&Wtl[di] = make_ushort4(l0, l1, l2, l3);
}

// ---------------- Kernel 1: fused conv + energy partial --------------------
__global__ __launch_bounds__(256, 3) void k_conv_energy(
    const float* __restrict__ x,
    const unsigned short* __restrict__ Wth, const unsigned short* __restrict__ Wtl,
    const float* __restrict__ bq, const float* __restrict__ bk,
    float* __restrict__ epart) {
  __shared__ unsigned short LDS[16384];   // 32 KiB, unioned across phases
  unsigned short* Th = LDS;               // energy chunk hi (256*32 u16)
  unsigned short* Tl = LDS + 8192;        // energy chunk lo

  const int t = threadIdx.x;
  const int nt = blockIdx.x, b = blockIdx.y;
  const int w = t >> 6, lane = t & 63;
  const int lrow = lane & 15, lkb = lane >> 4;

  const int pp = t >> 4;
  const int ci_l = pp >> 1, kh = pp & 1;
  const int i16 = t & 15;
  const int klb = ci_l * 4 + kh * 2;
  const float* xb = x + ((size_t)b << 21);
  const float* xrow = xb + (size_t)ci_l * 16384 + (2 * nt + kh) * 128 + 2 * i16;

  f32x4 acc[4][4];
#pragma unroll
  for (int m = 0; m < 4; ++m)
#pragma unroll
    for (int n = 0; n < 4; ++n) acc[m][n] = (f32x4){0.f, 0.f, 0.f, 0.f};

  s16x8 pfh[4], pfl[4];
  float2 pv[2][4];
  const int aoff = (w * 64 + lrow) * 32 + lkb * 8;

#pragma unroll
  for (int m = 0; m < 4; ++m) {
    pfh[m] = *(const s16x8*)&Wth[aoff + m * 512];
    pfl[m] = *(const s16x8*)&Wtl[aoff + m * 512];
  }
  {
    float2 v0 = *(const float2*)&xrow[0];
    float2 v1 = *(const float2*)&xrow[32];
    float2 v2 = *(const float2*)&xrow[64];
    float2 v3 = *(const float2*)&xrow[96];
    unsigned short hx, hy;
    hx = f2bf(v0.x); hy = f2bf(v0.y);
    *(unsigned*)&LDS[(i16     ) * 40 + klb] = pack2(hx, hy);
    *(unsigned*)&LDS[2560 + (i16     ) * 40 + klb] = pack2(f2bf(v0.x - bf2f(hx)), f2bf(v0.y - bf2f(hy)));
    hx = f2bf(v1.x); hy = f2bf(v1.y);
    *(unsigned*)&LDS[(i16 + 16) * 40 + klb] = pack2(hx, hy);
    *(unsigned*)&LDS[2560 + (i16 + 16) * 40 + klb] = pack2(f2bf(v1.x - bf2f(hx)), f2bf(v1.y - bf2f(hy)));
    hx = f2bf(v2.x); hy = f2bf(v2.y);
    *(unsigned*)&LDS[(i16 + 32) * 40 + klb] = pack2(hx, hy);
    *(unsigned*)&LDS[2560 + (i16 + 32) * 40 + klb] = pack2(f2bf(v2.x - bf2f(hx)), f2bf(v2.y - bf2f(hy)));
    hx = f2bf(v3.x); hy = f2bf(v3.y);
    *(unsigned*)&LDS[(i16 + 48) * 40 + klb] = pack2(hx, hy);
    *(unsigned*)&LDS[2560 + (i16 + 48) * 40 + klb] = pack2(f2bf(v3.x - bf2f(hx)), f2bf(v3.y - bf2f(hy)));
  }
#pragma unroll
  for (int g = 0; g < 4; ++g)
    pv[1][g] = *(const float2*)&xrow[(size_t)8 * 16384 + 32 * g];
  __syncthreads();

#pragma unroll
  for (int step = 0; step < 16; ++step) {
    const int cur = step & 1;
    const unsigned short* Bh = LDS + cur * 5120;
    const unsigned short* Bl = Bh + 2560;
    s16x8 bfh[4], bfl[4];
#pragma unroll
    for (int nf = 0; nf < 4; ++nf) {
      const int bidx = (nf * 16 + lrow) * 40 + lkb * 8;
      bfh[nf] = *(const s16x8*)&Bh[bidx];
      bfl[nf] = *(const s16x8*)&Bl[bidx];
    }
#pragma unroll
    for (int m = 0; m < 4; ++m)
#pragma unroll
      for (int n = 0; n < 4; ++n) {
        acc[m][n] = __builtin_amdgcn_mfma_f32_16x16x32_bf16(pfh[m], bfh[n], acc[m][n], 0, 0, 0);
        acc[m][n] = __builtin_amdgcn_mfma_f32_16x16x32_bf16(pfh[m], bfl[n], acc[m][n], 0, 0, 0);
        acc[m][n] = __builtin_amdgcn_mfma_f32_16x16x32_bf16(pfl[m], bfh[n], acc[m][n], 0, 0, 0);
      }
    if (step < 15) {
      const unsigned short* Wh_n = Wth + (step + 1) * 8192;
      const unsigned short* Wl_n = Wtl + (step + 1) * 8192;
#pragma unroll
      for (int m = 0; m < 4; ++m) {
        pfh[m] = *(const s16x8*)&Wh_n[aoff + m * 512];
        pfl[m] = *(const s16x8*)&Wl_n[aoff + m * 512];
      }
    }
    if (step < 14) {
#pragma unroll
      for (int g = 0; g < 4; ++g)
        pv[cur][g] = *(const float2*)&xrow[(size_t)(step + 2) * 8 * 16384 + 32 * g];
    }
    if (step < 15) {
      unsigned short* Nh = LDS + (cur ^ 1) * 5120;
      unsigned short* Nl = Nh + 2560;
#pragma unroll
      for (int g = 0; g < 4; ++g) {
        const int n = i16 + 16 * g;
        unsigned short hx = f2bf(pv[cur ^ 1][g].x), hy = f2bf(pv[cur ^ 1][g].y);
        *(unsigned*)&Nh[n * 40 + klb] = pack2(hx, hy);
        *(unsigned*)&Nl[n * 40 + klb] = pack2(f2bf(pv[cur ^ 1][g].x - bf2f(hx)),
                                              f2bf(pv[cur ^ 1][g].y - bf2f(hy)));
      }
      asm volatile("s_waitcnt lgkmcnt(0)" ::: "memory");
      __builtin_amdgcn_s_barrier();
    }
  }
  __syncthreads();

  const float* biasp = (w < 2) ? bq : bk;
  const int rb = (w & 1) * 64;
  float biasr[16];
#pragma unroll
  for (int m = 0; m < 4; ++m)
#pragma unroll
    for (int i = 0; i < 4; ++i)
      biasr[m * 4 + i] = biasp[rb + m * 16 + (lane >> 4) * 4 + i];

  f32x4 e[4][4];
#pragma unroll
  for (int m = 0; m < 4; ++m)
#pragma unroll
    for (int n = 0; n < 4; ++n) e[m][n] = (f32x4){0.f, 0.f, 0.f, 0.f};

  const int mrow0 = (w >> 1) * 64;
  const int nrow0 = 128 + (w & 1) * 64;

#pragma unroll
  for (int ks = 0; ks < 2; ++ks) {
#pragma unroll
    for (int m = 0; m < 4; ++m) {
      const int r0 = w * 64 + m * 16 + (lane >> 4) * 4;
#pragma unroll
      for (int nn = 0; nn < 2; ++nn) {
        const int n = 2 * ks + nn;
        const int cl = nn * 16 + lrow;
        const int cl8 = cl >> 3, c7 = cl & 7;
#pragma unroll
        for (int i = 0; i < 4; ++i) {
          const int r = r0 + i;
          const float vv = acc[m][n][i] + biasr[m * 4 + i];
          const unsigned short h = f2bf(vv);
          const unsigned short l = f2bf(vv - bf2f(h));
          const int ad = r * 32 + ((cl8 ^ (r & 3)) << 3) + c7;
          Th[ad] = h;
          Tl[ad] = l;
        }
      }
    }
    __syncthreads();
    {
      s16x8 qh[4], ql[4], kh8[4], kl8[4];
#pragma unroll
      for (int m = 0; m < 4; ++m) {
        const int r = mrow0 + m * 16 + lrow;
        const int ad = r * 32 + ((lkb ^ (r & 3)) << 3);
        qh[m] = *(const s16x8*)&Th[ad];
        ql[m] = *(const s16x8*)&Tl[ad];
      }
#pragma unroll
      for (int n = 0; n < 4; ++n) {
        const int r = nrow0 + n * 16 + lrow;
        const int ad = r * 32 + ((lkb ^ (r & 3)) << 3);
        kh8[n] = *(const s16x8*)&Th[ad];
        kl8[n] = *(const s16x8*)&Tl[ad];
      }
#pragma unroll
      for (int m = 0; m < 4; ++m)
#pragma unroll
        for (int n = 0; n < 4; ++n) {
          e[m][n] = __builtin_amdgcn_mfma_f32_16x16x32_bf16(qh[m], kh8[n], e[m][n], 0, 0, 0);
          e[m][n] = __builtin_amdgcn_mfma_f32_16x16x32_bf16(qh[m], kl8[n], e[m][n], 0, 0, 0);
          e[m][n] = __builtin_amdgcn_mfma_f32_16x16x32_bf16(ql[m], kh8[n], e[m][n], 0, 0, 0);
        }
    }
    if (ks == 0) __syncthreads();
  }

  float* ep = epart + ((size_t)b * 64 + nt) * 16384;
#pragma unroll
  for (int m = 0; m < 4; ++m) {
    const int qr = (w >> 1) * 64 + m * 16 + (lane >> 4) * 4;
#pragma unroll
    for (int n = 0; n < 4; ++n) {
      const int kr = (w & 1) * 64 + n * 16 + lrow;
#pragma unroll
      for (int i = 0; i < 4; ++i) ep[(size_t)(qr + i) * 128 + kr] = e[m][n][i];
    }
  }
}

// ---------------- Kernel 2: reduce + softmax + Mt(bf16 tiled) + ob ---------
__global__ __launch_bounds__(256) void k_softmax_M(
    const float* __restrict__ epart, const float* __restrict__ Wv,
    const float* __restrict__ bv, unsigned short* __restrict__ Mt,
    float* __restrict__ outbb) {
  __shared__ float As[4][128];
  const int t = threadIdx.x;
  const int wid = t >> 6, lane = t & 63;
  const int b = blockIdx.x >> 5;
  const int c = (blockIdx.x & 31) * 4 + wid;
  const int d0 = lane * 2;

  float2 s = make_float2(0.f, 0.f);
#pragma unroll 4
  for (int p = 0; p < 64; ++p) {
    float2 e = *(const float2*)&epart[((size_t)b * 64 + p) * 16384 + c * 128 + d0];
    s.x += e.x; s.y += e.y;
  }
  float mn = fminf(s.x, s.y);
#pragma unroll
  for (int off = 1; off < 64; off <<= 1) mn = fminf(mn, __shfl_xor(mn, off));
  const float p0 = expf(mn - s.x);
  const float p1 = expf(mn - s.y);
  float tot = p0 + p1;
#pragma unroll
  for (int off = 1; off < 64; off <<= 1) tot += __shfl_xor(tot, off);
  const float inv = 1.f / tot;
  const float a0 = p0 * inv, a1 = p1 * inv;

  const float2 bvv = *(const float2*)&bv[d0];
  float ob = a0 * bvv.x + a1 * bvv.y;
#pragma unroll
  for (int off = 1; off < 64; off <<= 1) ob += __shfl_xor(ob, off);
  if (lane == 0) outbb[b * 128 + c] = ob;

  As[wid][d0] = a0;
  As[wid][d0 + 1] = a1;   // wave-local write->read, lockstep-safe
  float m0 = 0.f, m1 = 0.f;
#pragma unroll 4
  for (int d = 0; d < 128; ++d) {
    const float a = As[wid][d];
    const float2 wv = *(const float2*)&Wv[d * 128 + d0];
    m0 = fmaf(a, wv.x, m0);
    m1 = fmaf(a, wv.y, m1);
  }
  const int sk = lane >> 4;
  const int ko = (lane * 2) & 31;
  *(unsigned*)&Mt[(size_t)b * 16384 + sk * 4096 + c * 32 + ko] =
      pack2(f2bf(m0), f2bf(m1));
}

// ---------------- Kernel 3: out = Mt @ X + ob ------------------------------
__global__ __launch_bounds__(256) void k_out(
    const float* __restrict__ x, const unsigned short* __restrict__ Mt,
    const float* __restrict__ outbb, float* __restrict__ out) {
  __shared__ unsigned short Xs[10240];
  const int t = threadIdx.x;
  const int nt = blockIdx.x, b = blockIdx.y;
  const int wid = t >> 6, lane = t & 63;
  const int wr = wid >> 1, wc = wid & 1;
  const int lrow = lane & 15, lkb = lane >> 4;
  const int xkl = (t >> 5) * 4;
  const int xc0 = (t & 31) * 4;

  const float* xb = x + ((size_t)b << 21);
  const unsigned short* Mb = Mt + (size_t)b * 16384;
  float* ob = out + ((size_t)b << 21);

  f32x4 acc[4][4];
#pragma unroll
  for (int m = 0; m < 4; ++m)
#pragma unroll
    for (int n = 0; n < 4; ++n) acc[m][n] = (f32x4){0.f, 0.f, 0.f, 0.f};

  float4 pv[2][4];
#pragma unroll
  for (int q = 0; q < 4; ++q) {
    float4 v = *(const float4*)&xb[(size_t)(xkl + q) * 16384 + nt * 128 + xc0];
    Xs[(xc0 + 0) * 40 + xkl + q] = f2bf(v.x);
    Xs[(xc0 + 1) * 40 + xkl + q] = f2bf(v.y);
    Xs[(xc0 + 2) * 40 + xkl + q] = f2bf(v.z);
    Xs[(xc0 + 3) * 40 + xkl + q] = f2bf(v.w);
  }
#pragma unroll
  for (int q = 0; q < 4; ++q)
    pv[1][q] = *(const float4*)&xb[(size_t)(32 + xkl + q) * 16384 + nt * 128 + xc0];
  __syncthreads();

#pragma unroll
  for (int step = 0; step < 4; ++step) {
    const int cur = step & 1;
    const unsigned short* Bx = Xs + cur * 5120;
    s16x8 bf[4];
#pragma unroll
    for (int n = 0; n < 4; ++n)
      bf[n] = *(const s16x8*)&Bx[(wc * 64 + n * 16 + lrow) * 40 + lkb * 8];
    s16x8 af[4];
#pragma unroll
    for (int m = 0; m < 4; ++m)
      af[m] = *(const s16x8*)&Mb[step * 4096 + (wr * 64 + m * 16 + lrow) * 32 + lkb * 8];
    if (step < 2) {
#pragma unroll
      for (int q = 0; q < 4; ++q)
        pv[cur][q] = *(const float4*)&xb[(size_t)((step + 2) * 32 + xkl + q) * 16384 + nt * 128 + xc0];
    }
#pragma unroll
    for (int m = 0; m < 4; ++m)
#pragma unroll
      for (int n = 0; n < 4; ++n)
        acc[m][n] = __builtin_amdgcn_mfma_f32_16x16x32_bf16(af[m], bf[n], acc[m][n], 0, 0, 0);
    if (step < 3) {
      unsigned short* Nx = Xs + (cur ^ 1) * 5120;
#pragma unroll
      for (int q = 0; q < 4; ++q) {
        Nx[(xc0 + 0) * 40 + xkl + q] = f2bf(pv[cur ^ 1][q].x);
        Nx[(xc0 + 1) * 40 + xkl + q] = f2bf(pv[cur ^ 1][q].y);
        Nx[(xc0 + 2) * 40 + xkl + q] = f2bf(pv[cur ^ 1][q].z);
        Nx[(xc0 + 3) * 40 + xkl + q] = f2bf(pv[cur ^ 1][q].w);
      }
      asm volatile("s_waitcnt lgkmcnt(0)" ::: "memory");
      __builtin_amdgcn_s_barrier();
    }
  }
#pragma unroll
  for (int m = 0; m < 4; ++m) {
    const int r0 = wr * 64 + m * 16 + (lane >> 4) * 4;
#pragma unroll
    for (int n = 0; n < 4; ++n) {
      const int gc = nt * 128 + wc * 64 + n * 16 + (lane & 15);
#pragma unroll
      for (int i = 0; i < 4; ++i) {
        const int row = r0 + i;
        ob[(size_t)row * 16384 + gc] = acc[m][n][i] + outbb[b * 128 + row];
      }
    }
  }
}

// ---------------------------------------------------------------------------
extern "C" void kernel_launch(void* const* d_in, const int* in_sizes, int n_in,
                              void* d_out, int out_size, void* d_ws, size_t ws_size,
                              hipStream_t stream) {
  const float* x  = (const float*)d_in[0];
  const float* Wq = (const float*)d_in[1];
  const float* bq = (const float*)d_in[2];
  const float* Wk = (const float*)d_in[3];
  const float* bk = (const float*)d_in[4];
  const float* Wv = (const float*)d_in[5];
  const float* bv = (const float*)d_in[6];
  float* out = (float*)d_out;
  char* ws = (char*)d_ws;

  float* epart = (float*)ws;                               // 32 MiB
  unsigned short* Mt = (unsigned short*)(ws + 33554432);   // 256 KiB (bf16)
  float* outbb = (float*)(ws + 33816576);                  // 4 KiB
  unsigned short* Wth = (unsigned short*)(ws + 33820672);  // 256 KiB
  unsigned short* Wtl = (unsigned short*)(ws + 34082816);  // 256 KiB

  hipLaunchKernelGGL(k_prep, dim3(128), dim3(256), 0, stream, Wq, Wk, Wth, Wtl);
  hipLaunchKernelGGL(k_conv_energy, dim3(64, 8), dim3(256), 0, stream,
                     x, Wth, Wtl, bq, bk, epart);
  hipLaunchKernelGGL(k_softmax_M, dim3(256), dim3(256), 0, stream,
                     epart, Wv, bv, Mt, outbb);
  hipLaunchKernelGGL(k_out, dim3(128, 8), dim3(256), 0, stream,
                     x, Mt, outbb, out);
}